// Round 2
// baseline (49.291 us; speedup 1.0000x reference)
//
#include <hip/hip_runtime.h>
#include <hip/hip_bf16.h>
#include <cstdint>

#define DIM 128

__device__ __forceinline__ float prelu(float x, float a) {
    return x >= 0.f ? x : a * x;
}

// Fully-fused tree encoder. Key fact: the output [B,128] depends only on
//   h1 at {cl0[0], cr0[0]}          (2 rows/batch)
//   h2 at {cl1/cr1 of those, cs0[0]} (5 rows/batch)
//   h3 at {cl2/cr2 of those, cs1 of the 2 layer-1 rows} (12 rows/batch)
// so we compute exactly those rows. One block per batch element,
// 256 threads = (h = which half of the 256-wide concat dim) x (k = out chan).
__global__ __launch_bounds__(256) void encoder_fused(
    const float* __restrict__ points,
    const float* __restrict__ vec2, const float* __restrict__ vec1,
    const float* __restrict__ vec0,
    const float* __restrict__ Wp,  const float* __restrict__ bp,
    const float* __restrict__ aL,
    const float* __restrict__ Wb2, const float* __restrict__ bb2,
    const float* __restrict__ a2,
    const float* __restrict__ Wb1, const float* __restrict__ bb1,
    const float* __restrict__ Ws1, const float* __restrict__ bs1,
    const float* __restrict__ a1,
    const float* __restrict__ Wb0, const float* __restrict__ bb0,
    const float* __restrict__ Ws0, const float* __restrict__ bs0,
    const float* __restrict__ a0,
    const int* __restrict__ cl2, const int* __restrict__ cr2,
    const int* __restrict__ cl1, const int* __restrict__ cr1,
    const int* __restrict__ cs1,
    const int* __restrict__ cl0, const int* __restrict__ cr0,
    const int* __restrict__ cs0,
    float* __restrict__ out,
    int N3, int N2, int N1)
{
    __shared__ float leaf[12][DIM];   // needed h3 rows
    __shared__ float h2s[5][DIM];     // needed h2 rows
    __shared__ float t1s[2][DIM];     // layer-1 bilinear outputs
    __shared__ float h1s[2][DIM];     // layer-1 final outputs
    __shared__ float h0s[DIM];        // root bilinear output
    __shared__ float part[2 * 5 * 3 * DIM];  // reduction scratch (reused)

    int b = blockIdx.x;
    int t = threadIdx.x;
    int h = t >> 7;       // half of the 256-wide concat dim
    int k = t & 127;      // output channel

    // ---- uniform index resolution (3-deep dependent gather chain) ----
    int m[2];
    m[0] = cl0[0];
    m[1] = cr0[0];
    int nj[5];
    nj[0] = cl1[m[0]]; nj[1] = cr1[m[0]];
    nj[2] = cl1[m[1]]; nj[3] = cr1[m[1]];
    nj[4] = cs0[0];
    int lj[12];
#pragma unroll
    for (int j = 0; j < 5; ++j) {
        lj[2 * j]     = cl2[nj[j]];
        lj[2 * j + 1] = cr2[nj[j]];
    }
    lj[10] = cs1[m[0]];
    lj[11] = cs1[m[1]];

    // ---- leaf rows: leaf[r][k] = prelu(points[lj[r]] . Wp[k] + bp[k]) ----
    {
        float aLv = aL[0];
        float wp0 = Wp[k * 3 + 0], wp1 = Wp[k * 3 + 1], wp2 = Wp[k * 3 + 2];
        float bpv = bp[k];
#pragma unroll
        for (int it = 0; it < 6; ++it) {
            int r = it * 2 + h;
            size_t pb = ((size_t)b * N3 + lj[r]) * 3;
            float p0 = points[pb], p1 = points[pb + 1], p2 = points[pb + 2];
            leaf[r][k] = prelu(p0 * wp0 + p1 * wp1 + p2 * wp2 + bpv, aLv);
        }
    }
    __syncthreads();

    // ---- layer 2: 5 bilinear rows, d-split across h ----
    {
        float acc[5][3] = {};
        const float* wr = Wb2 + (size_t)k * 768 + h * 384;  // W[k][d=h*128+d0][v]
        for (int d0 = 0; d0 < 128; ++d0) {
            float w0 = wr[d0 * 3 + 0], w1 = wr[d0 * 3 + 1], w2 = wr[d0 * 3 + 2];
#pragma unroll
            for (int j = 0; j < 5; ++j) {
                float xd = leaf[2 * j + h][d0];  // x2 = concat(h3[cl2], h3[cr2])
                acc[j][0] += w0 * xd;
                acc[j][1] += w1 * xd;
                acc[j][2] += w2 * xd;
            }
        }
#pragma unroll
        for (int j = 0; j < 5; ++j)
#pragma unroll
            for (int v = 0; v < 3; ++v)
                part[((h * 5 + j) * 3 + v) * DIM + k] = acc[j][v];
    }
    __syncthreads();
    {
        float a2v = a2[0];
        for (int jk = t; jk < 5 * DIM; jk += 256) {
            int j = jk >> 7, kk = jk & 127;
            size_t vb = ((size_t)b * N2 + nj[j]) * 3;
            float z = bb2[kk];
#pragma unroll
            for (int v = 0; v < 3; ++v)
                z += vec2[vb + v] * (part[((0 * 5 + j) * 3 + v) * DIM + kk] +
                                     part[((1 * 5 + j) * 3 + v) * DIM + kk]);
            h2s[j][kk] = prelu(z, a2v);
        }
    }
    __syncthreads();

    // ---- layer 1 bilinear: 2 nodes; x1 = concat(h2s[2i], h2s[2i+1]) ----
    {
        float acc[2][3] = {};
        const float* wr = Wb1 + (size_t)k * 768 + h * 384;
        for (int d0 = 0; d0 < 128; ++d0) {
            float w0 = wr[d0 * 3 + 0], w1 = wr[d0 * 3 + 1], w2 = wr[d0 * 3 + 2];
#pragma unroll
            for (int i = 0; i < 2; ++i) {
                float xd = h2s[2 * i + h][d0];
                acc[i][0] += w0 * xd;
                acc[i][1] += w1 * xd;
                acc[i][2] += w2 * xd;
            }
        }
#pragma unroll
        for (int i = 0; i < 2; ++i)
#pragma unroll
            for (int v = 0; v < 3; ++v)
                part[((h * 2 + i) * 3 + v) * DIM + k] = acc[i][v];
    }
    __syncthreads();
    {
        // 256 outputs: node i = h, channel kk = k
        float a1v = a1[0];
        size_t vb = ((size_t)b * N1 + m[h]) * 3;
        float z = bb1[k];
#pragma unroll
        for (int v = 0; v < 3; ++v)
            z += vec1[vb + v] * (part[((0 * 2 + h) * 3 + v) * DIM + k] +
                                 part[((1 * 2 + h) * 3 + v) * DIM + k]);
        t1s[h][k] = prelu(z, a1v);
    }
    __syncthreads();

    // ---- layer 1 sampled linear: concat(t1s[i], leaf[10+i]) . Ws1[k] ----
    {
        float s0 = 0.f, s1 = 0.f;
        const float* wr  = Ws1 + (size_t)k * 256 + h * 128;
        const float* x0p = h ? leaf[10] : t1s[0];
        const float* x1p = h ? leaf[11] : t1s[1];
        for (int d0 = 0; d0 < 128; ++d0) {
            float w = wr[d0];
            s0 += w * x0p[d0];
            s1 += w * x1p[d0];
        }
        part[(h * 2 + 0) * DIM + k] = s0;
        part[(h * 2 + 1) * DIM + k] = s1;
    }
    __syncthreads();
    {
        float a1v = a1[0];
        h1s[h][k] = prelu(part[(0 * 2 + h) * DIM + k] +
                          part[(1 * 2 + h) * DIM + k] + bs1[k], a1v);
    }
    __syncthreads();

    // ---- root bilinear: x0 = concat(h1s[0], h1s[1]) ----
    {
        float acc0 = 0.f, acc1 = 0.f, acc2 = 0.f;
        const float* wr = Wb0 + (size_t)k * 768 + h * 384;
        const float* xp = h1s[h];
        for (int d0 = 0; d0 < 128; ++d0) {
            float xd = xp[d0];
            acc0 += wr[d0 * 3 + 0] * xd;
            acc1 += wr[d0 * 3 + 1] * xd;
            acc2 += wr[d0 * 3 + 2] * xd;
        }
        part[(h * 3 + 0) * DIM + k] = acc0;
        part[(h * 3 + 1) * DIM + k] = acc1;
        part[(h * 3 + 2) * DIM + k] = acc2;
    }
    __syncthreads();
    if (t < 128) {
        float a0v = a0[0];
        float z = bb0[k];
#pragma unroll
        for (int v = 0; v < 3; ++v)
            z += vec0[b * 3 + v] * (part[(0 * 3 + v) * DIM + k] +
                                    part[(1 * 3 + v) * DIM + k]);
        h0s[k] = prelu(z, a0v);
    }
    __syncthreads();

    // ---- root sampled linear: concat(h0s, h2s[4]) . Ws0[k] ----
    {
        float s = 0.f;
        const float* wr = Ws0 + (size_t)k * 256 + h * 128;
        const float* xp = h ? h2s[4] : h0s;
        for (int d0 = 0; d0 < 128; ++d0) s += wr[d0] * xp[d0];
        part[h * DIM + k] = s;
    }
    __syncthreads();
    if (t < 128) {
        float a0v = a0[0];
        out[(size_t)b * DIM + t] = prelu(part[t] + part[DIM + t] + bs0[t], a0v);
    }
}

// ---------------- launch ---------------------------------------------------
extern "C" void kernel_launch(void* const* d_in, const int* in_sizes, int n_in,
                              void* d_out, int out_size, void* d_ws, size_t ws_size,
                              hipStream_t stream)
{
    const float* points = (const float*)d_in[0];
    const float* vec2   = (const float*)d_in[1];
    const float* vec1   = (const float*)d_in[2];
    const float* vec0   = (const float*)d_in[3];
    const float* Wp     = (const float*)d_in[4];
    const float* bp     = (const float*)d_in[5];
    const float* a_leaf = (const float*)d_in[6];
    const float* Wb2    = (const float*)d_in[7];
    const float* bb2    = (const float*)d_in[8];
    const float* a2     = (const float*)d_in[9];
    const float* Wb1    = (const float*)d_in[10];
    const float* bb1    = (const float*)d_in[11];
    const float* Ws1    = (const float*)d_in[12];
    const float* bs1    = (const float*)d_in[13];
    const float* a1     = (const float*)d_in[14];
    const float* Wb0    = (const float*)d_in[15];
    const float* bb0    = (const float*)d_in[16];
    const float* Ws0    = (const float*)d_in[17];
    const float* bs0    = (const float*)d_in[18];
    const float* a0     = (const float*)d_in[19];
    const int* cl2 = (const int*)d_in[20];
    const int* cr2 = (const int*)d_in[21];
    const int* cl1 = (const int*)d_in[22];
    const int* cr1 = (const int*)d_in[23];
    const int* cs1 = (const int*)d_in[24];
    const int* cl0 = (const int*)d_in[25];
    const int* cr0 = (const int*)d_in[26];
    const int* cs0 = (const int*)d_in[27];

    const int B = 8, N3 = 131072, N2 = 65536, N1 = 1024;
    (void)d_ws; (void)ws_size; (void)in_sizes; (void)n_in; (void)out_size;

    encoder_fused<<<B, 256, 0, stream>>>(
        points, vec2, vec1, vec0,
        Wp, bp, a_leaf,
        Wb2, bb2, a2,
        Wb1, bb1, Ws1, bs1, a1,
        Wb0, bb0, Ws0, bs0, a0,
        cl2, cr2, cl1, cr1, cs1, cl0, cr0, cs0,
        (float*)d_out, N3, N2, N1);
}

// Round 3
// 48.215 us; speedup vs baseline: 1.0223x; 1.0223x over previous
//
#include <hip/hip_runtime.h>
#include <hip/hip_bf16.h>
#include <cstdint>

#define DIM 128

__device__ __forceinline__ float prelu(float x, float a) {
    return x >= 0.f ? x : a * x;
}

// Fully-fused dead-code-eliminated tree encoder.
// Output [B,128] depends only on: 2 h1 rows, 5 h2 rows, 12 h3 rows per batch.
// One block per batch, 1024 threads = (h = d-chunk of 32, 8 ways) x (k = 128).
// Weight loads are register-batched float4 (12 outstanding per round) so each
// stage pays ~2 latency round-trips instead of 128.
__global__ __launch_bounds__(1024) void encoder_fused(
    const float* __restrict__ points,
    const float* __restrict__ vec2, const float* __restrict__ vec1,
    const float* __restrict__ vec0,
    const float* __restrict__ Wp,  const float* __restrict__ bp,
    const float* __restrict__ aL,
    const float* __restrict__ Wb2, const float* __restrict__ bb2,
    const float* __restrict__ a2,
    const float* __restrict__ Wb1, const float* __restrict__ bb1,
    const float* __restrict__ Ws1, const float* __restrict__ bs1,
    const float* __restrict__ a1,
    const float* __restrict__ Wb0, const float* __restrict__ bb0,
    const float* __restrict__ Ws0, const float* __restrict__ bs0,
    const float* __restrict__ a0,
    const int* __restrict__ cl2, const int* __restrict__ cr2,
    const int* __restrict__ cl1, const int* __restrict__ cr1,
    const int* __restrict__ cs1,
    const int* __restrict__ cl0, const int* __restrict__ cr0,
    const int* __restrict__ cs0,
    float* __restrict__ out,
    int N3, int N2, int N1)
{
    __shared__ float leaf[12][DIM];   // needed h3 rows
    __shared__ float h2s[5][DIM];     // needed h2 rows (0..3: L1 children, 4: cs0)
    __shared__ float t1s[2][DIM];     // layer-1 bilinear outputs
    __shared__ float h1s[2][DIM];     // layer-1 final outputs
    __shared__ float h0s[DIM];        // root bilinear output
    __shared__ float part[8 * 5 * DIM];  // cross-h partials (max: layer2, 20KB)
    __shared__ int   ljs[12];         // leaf row indices (LDS: dynamic-indexed)

    const int b = blockIdx.x;
    const int t = threadIdx.x;
    const int h  = t >> 7;        // d-chunk 0..7 (32 dims each)
    const int k  = t & 127;       // output channel
    const int hr = h >> 2;        // which half of the 256-wide concat
    const int ho = (h & 3) * 32;  // float offset within the 128-wide half

    // ---- uniform index chain (SGPR scalar loads) ----
    const int m0 = cl0[0], m1 = cr0[0];
    int nj[5];
    nj[0] = cl1[m0]; nj[1] = cr1[m0];
    nj[2] = cl1[m1]; nj[3] = cr1[m1];
    nj[4] = cs0[0];
    if (t == 0) {
        ljs[0] = cl2[nj[0]]; ljs[1] = cr2[nj[0]];
        ljs[2] = cl2[nj[1]]; ljs[3] = cr2[nj[1]];
        ljs[4] = cl2[nj[2]]; ljs[5] = cr2[nj[2]];
        ljs[6] = cl2[nj[3]]; ljs[7] = cr2[nj[3]];
        ljs[8] = cl2[nj[4]]; ljs[9] = cr2[nj[4]];
        ljs[10] = cs1[m0];   ljs[11] = cs1[m1];
    }
    __syncthreads();

    // ---- leaf rows: leaf[r][kk] = prelu(points[ljs[r]] . Wp[kk] + bp[kk]) ----
    {
        float aLv = aL[0];
        for (int idx = t; idx < 12 * DIM; idx += 1024) {
            int r = idx >> 7, kk = idx & 127;
            size_t pb = ((size_t)b * N3 + ljs[r]) * 3;
            float p0 = points[pb], p1 = points[pb + 1], p2 = points[pb + 2];
            leaf[r][kk] = prelu(p0 * Wp[kk * 3 + 0] + p1 * Wp[kk * 3 + 1] +
                                p2 * Wp[kk * 3 + 2] + bp[kk], aLv);
        }
    }
    __syncthreads();

    // ---- layer 2: 5 bilinear nodes, d split 8 ways ----
    {
        float acc[5][3] = {};
        const float* wbase = Wb2 + (size_t)k * 768 + h * 96;
#pragma unroll
        for (int c = 0; c < 2; ++c) {
            float w[48];
#pragma unroll
            for (int i = 0; i < 12; ++i) {
                float4 v4 = *reinterpret_cast<const float4*>(wbase + c * 48 + i * 4);
                w[i * 4 + 0] = v4.x; w[i * 4 + 1] = v4.y;
                w[i * 4 + 2] = v4.z; w[i * 4 + 3] = v4.w;
            }
#pragma unroll
            for (int j = 0; j < 5; ++j) {
                const float* xr = &leaf[2 * j + hr][ho + c * 16];
                float x[16];
#pragma unroll
                for (int i2 = 0; i2 < 4; ++i2) {
                    float4 xv = *reinterpret_cast<const float4*>(xr + i2 * 4);
                    x[i2 * 4 + 0] = xv.x; x[i2 * 4 + 1] = xv.y;
                    x[i2 * 4 + 2] = xv.z; x[i2 * 4 + 3] = xv.w;
                }
#pragma unroll
                for (int dl = 0; dl < 16; ++dl) {
                    acc[j][0] += w[dl * 3 + 0] * x[dl];
                    acc[j][1] += w[dl * 3 + 1] * x[dl];
                    acc[j][2] += w[dl * 3 + 2] * x[dl];
                }
            }
        }
#pragma unroll
        for (int j = 0; j < 5; ++j) {
            size_t vb = ((size_t)b * N2 + nj[j]) * 3;
            float z = vec2[vb + 0] * acc[j][0] + vec2[vb + 1] * acc[j][1] +
                      vec2[vb + 2] * acc[j][2];
            part[(h * 5 + j) * DIM + k] = z;
        }
    }
    __syncthreads();
    if (t < 5 * DIM) {
        float a2v = a2[0];
        int j = t >> 7, kk = t & 127;
        float s = bb2[kk];
#pragma unroll
        for (int hh = 0; hh < 8; ++hh) s += part[(hh * 5 + j) * DIM + kk];
        h2s[j][kk] = prelu(s, a2v);
    }
    __syncthreads();

    // ---- layer 1 bilinear: 2 nodes ----
    {
        float acc[2][3] = {};
        const float* wbase = Wb1 + (size_t)k * 768 + h * 96;
#pragma unroll
        for (int c = 0; c < 2; ++c) {
            float w[48];
#pragma unroll
            for (int i = 0; i < 12; ++i) {
                float4 v4 = *reinterpret_cast<const float4*>(wbase + c * 48 + i * 4);
                w[i * 4 + 0] = v4.x; w[i * 4 + 1] = v4.y;
                w[i * 4 + 2] = v4.z; w[i * 4 + 3] = v4.w;
            }
#pragma unroll
            for (int i = 0; i < 2; ++i) {
                const float* xr = &h2s[2 * i + hr][ho + c * 16];
                float x[16];
#pragma unroll
                for (int i2 = 0; i2 < 4; ++i2) {
                    float4 xv = *reinterpret_cast<const float4*>(xr + i2 * 4);
                    x[i2 * 4 + 0] = xv.x; x[i2 * 4 + 1] = xv.y;
                    x[i2 * 4 + 2] = xv.z; x[i2 * 4 + 3] = xv.w;
                }
#pragma unroll
                for (int dl = 0; dl < 16; ++dl) {
                    acc[i][0] += w[dl * 3 + 0] * x[dl];
                    acc[i][1] += w[dl * 3 + 1] * x[dl];
                    acc[i][2] += w[dl * 3 + 2] * x[dl];
                }
            }
        }
#pragma unroll
        for (int i = 0; i < 2; ++i) {
            size_t vb = ((size_t)b * N1 + (i ? m1 : m0)) * 3;
            float z = vec1[vb + 0] * acc[i][0] + vec1[vb + 1] * acc[i][1] +
                      vec1[vb + 2] * acc[i][2];
            part[(h * 2 + i) * DIM + k] = z;
        }
    }
    __syncthreads();
    if (t < 2 * DIM) {
        float a1v = a1[0];
        int i = t >> 7, kk = t & 127;
        float s = bb1[kk];
#pragma unroll
        for (int hh = 0; hh < 8; ++hh) s += part[(hh * 2 + i) * DIM + kk];
        t1s[i][kk] = prelu(s, a1v);
    }
    __syncthreads();

    // ---- layer 1 sampled linear: concat(t1s[i], leaf[10+i]) . Ws1[k] ----
    {
        float acc0 = 0.f, acc1 = 0.f;
        const float* wb = Ws1 + (size_t)k * 256 + h * 32;
        float w[32];
#pragma unroll
        for (int i = 0; i < 8; ++i) {
            float4 v4 = *reinterpret_cast<const float4*>(wb + i * 4);
            w[i * 4 + 0] = v4.x; w[i * 4 + 1] = v4.y;
            w[i * 4 + 2] = v4.z; w[i * 4 + 3] = v4.w;
        }
        const float* x0r = hr == 0 ? &t1s[0][ho] : &leaf[10][ho];
        const float* x1r = hr == 0 ? &t1s[1][ho] : &leaf[11][ho];
#pragma unroll
        for (int dl = 0; dl < 32; ++dl) {
            acc0 += w[dl] * x0r[dl];
            acc1 += w[dl] * x1r[dl];
        }
        part[(h * 2 + 0) * DIM + k] = acc0;
        part[(h * 2 + 1) * DIM + k] = acc1;
    }
    __syncthreads();
    if (t < 2 * DIM) {
        float a1v = a1[0];
        int i = t >> 7, kk = t & 127;
        float s = bs1[kk];
#pragma unroll
        for (int hh = 0; hh < 8; ++hh) s += part[(hh * 2 + i) * DIM + kk];
        h1s[i][kk] = prelu(s, a1v);
    }
    __syncthreads();

    // ---- root bilinear: x0 = concat(h1s[0], h1s[1]) ----
    {
        float ac0 = 0.f, ac1 = 0.f, ac2 = 0.f;
        const float* wbase = Wb0 + (size_t)k * 768 + h * 96;
#pragma unroll
        for (int c = 0; c < 2; ++c) {
            float w[48];
#pragma unroll
            for (int i = 0; i < 12; ++i) {
                float4 v4 = *reinterpret_cast<const float4*>(wbase + c * 48 + i * 4);
                w[i * 4 + 0] = v4.x; w[i * 4 + 1] = v4.y;
                w[i * 4 + 2] = v4.z; w[i * 4 + 3] = v4.w;
            }
            const float* xr = &h1s[hr][ho + c * 16];
            float x[16];
#pragma unroll
            for (int i2 = 0; i2 < 4; ++i2) {
                float4 xv = *reinterpret_cast<const float4*>(xr + i2 * 4);
                x[i2 * 4 + 0] = xv.x; x[i2 * 4 + 1] = xv.y;
                x[i2 * 4 + 2] = xv.z; x[i2 * 4 + 3] = xv.w;
            }
#pragma unroll
            for (int dl = 0; dl < 16; ++dl) {
                ac0 += w[dl * 3 + 0] * x[dl];
                ac1 += w[dl * 3 + 1] * x[dl];
                ac2 += w[dl * 3 + 2] * x[dl];
            }
        }
        float z = vec0[b * 3 + 0] * ac0 + vec0[b * 3 + 1] * ac1 +
                  vec0[b * 3 + 2] * ac2;
        part[h * DIM + k] = z;
    }
    __syncthreads();
    if (t < DIM) {
        float a0v = a0[0];
        float s = bb0[t];
#pragma unroll
        for (int hh = 0; hh < 8; ++hh) s += part[hh * DIM + t];
        h0s[t] = prelu(s, a0v);
    }
    __syncthreads();

    // ---- root sampled linear: concat(h0s, h2s[4]) . Ws0[k] ----
    {
        float acc = 0.f;
        const float* wb = Ws0 + (size_t)k * 256 + h * 32;
        float w[32];
#pragma unroll
        for (int i = 0; i < 8; ++i) {
            float4 v4 = *reinterpret_cast<const float4*>(wb + i * 4);
            w[i * 4 + 0] = v4.x; w[i * 4 + 1] = v4.y;
            w[i * 4 + 2] = v4.z; w[i * 4 + 3] = v4.w;
        }
        const float* xr = hr == 0 ? &h0s[ho] : &h2s[4][ho];
#pragma unroll
        for (int dl = 0; dl < 32; ++dl) acc += w[dl] * xr[dl];
        part[h * DIM + k] = acc;
    }
    __syncthreads();
    if (t < DIM) {
        float a0v = a0[0];
        float s = bs0[t];
#pragma unroll
        for (int hh = 0; hh < 8; ++hh) s += part[hh * DIM + t];
        out[(size_t)b * DIM + t] = prelu(s, a0v);
    }
}

// ---------------- launch ---------------------------------------------------
extern "C" void kernel_launch(void* const* d_in, const int* in_sizes, int n_in,
                              void* d_out, int out_size, void* d_ws, size_t ws_size,
                              hipStream_t stream)
{
    const float* points = (const float*)d_in[0];
    const float* vec2   = (const float*)d_in[1];
    const float* vec1   = (const float*)d_in[2];
    const float* vec0   = (const float*)d_in[3];
    const float* Wp     = (const float*)d_in[4];
    const float* bp     = (const float*)d_in[5];
    const float* a_leaf = (const float*)d_in[6];
    const float* Wb2    = (const float*)d_in[7];
    const float* bb2    = (const float*)d_in[8];
    const float* a2     = (const float*)d_in[9];
    const float* Wb1    = (const float*)d_in[10];
    const float* bb1    = (const float*)d_in[11];
    const float* Ws1    = (const float*)d_in[12];
    const float* bs1    = (const float*)d_in[13];
    const float* a1     = (const float*)d_in[14];
    const float* Wb0    = (const float*)d_in[15];
    const float* bb0    = (const float*)d_in[16];
    const float* Ws0    = (const float*)d_in[17];
    const float* bs0    = (const float*)d_in[18];
    const float* a0     = (const float*)d_in[19];
    const int* cl2 = (const int*)d_in[20];
    const int* cr2 = (const int*)d_in[21];
    const int* cl1 = (const int*)d_in[22];
    const int* cr1 = (const int*)d_in[23];
    const int* cs1 = (const int*)d_in[24];
    const int* cl0 = (const int*)d_in[25];
    const int* cr0 = (const int*)d_in[26];
    const int* cs0 = (const int*)d_in[27];

    const int B = 8, N3 = 131072, N2 = 65536, N1 = 1024;
    (void)d_ws; (void)ws_size; (void)in_sizes; (void)n_in; (void)out_size;

    encoder_fused<<<B, 1024, 0, stream>>>(
        points, vec2, vec1, vec0,
        Wp, bp, a_leaf,
        Wb2, bb2, a2,
        Wb1, bb1, Ws1, bs1, a1,
        Wb0, bb0, Ws0, bs0, a0,
        cl2, cr2, cl1, cr1, cs1, cl0, cr0, cs0,
        (float*)d_out, N3, N2, N1);
}

// Round 4
// 25.862 us; speedup vs baseline: 1.9059x; 1.8643x over previous
//
#include <hip/hip_runtime.h>
#include <hip/hip_bf16.h>
#include <cstdint>

#define DIM 128

#define BARRIER() asm volatile("s_barrier" ::: "memory")
#define WAITV3()  asm volatile("s_waitcnt vmcnt(3)" ::: "memory")
#define WAITV0()  asm volatile("s_waitcnt vmcnt(0)" ::: "memory")

__device__ __forceinline__ float prelu(float x, float a) {
    return x >= 0.f ? x : a * x;
}

// Stage one 48KB d-chunk of a bilinear weight W[128][256][3] into LDS.
// Chunk c covers d in [32c, 32c+32). Global per-k segment = 96 contiguous
// floats (24 x 16B units). LDS dest is linear (global_load_lds requirement);
// the 16B-unit index is XOR-swizzled against (k&7) on the GLOBAL side so the
// swizzled ds_read spreads banks (rule: pre-swizzle source, swizzle read).
__device__ __forceinline__ void stage_wb_chunk(const float* __restrict__ W,
                                               int c, float* buf, int t) {
#pragma unroll
    for (int s = 0; s < 3; ++s) {
        int unit = s * 1024 + t;             // 0..3071 (3072 units = 48KB)
        int k = (unit * 2731) >> 16;         // unit / 24  (exact for unit<3072)
        int q = unit - k * 24;               // unit % 24
        int qs = q ^ (k & 7);                // swizzled within 8-aligned groups
        const float* src = W + (size_t)k * 768 + c * 96 + qs * 4;
        float* dst = buf + ((s * 1024 + (t & ~63)) << 2);  // wave-uniform base
        __builtin_amdgcn_global_load_lds(
            (const __attribute__((address_space(1))) void*)src,
            (__attribute__((address_space(3))) void*)dst, 16, 0, 0);
    }
}

// One 32-d chunk of bilinear accumulation. Thread (k,u) handles d-slice
// [32c+4u, 32c+4u+4) for all J nodes, all 3 v. Weights read from staged LDS
// with the matching XOR swizzle; x rows read b128 (8-way k-broadcast, free).
template<int J>
__device__ __forceinline__ void bilin_chunk(const float* buf, int c,
                                            const float* xbase, int k, int u,
                                            float acc[][3]) {
    const int sw = k & 7;
    const int bu = k * 24 + u * 3;
    float4 w0 = *reinterpret_cast<const float4*>(buf + (((bu + 0) ^ sw) << 2));
    float4 w1 = *reinterpret_cast<const float4*>(buf + (((bu + 1) ^ sw) << 2));
    float4 w2 = *reinterpret_cast<const float4*>(buf + (((bu + 2) ^ sw) << 2));
    const int inner = ((c & 3) << 5) + (u << 2);
    const int half = c >> 2;   // which 128-row of the 256-wide concat
#pragma unroll
    for (int j = 0; j < J; ++j) {
        float4 xv = *reinterpret_cast<const float4*>(
            xbase + (2 * j + half) * 128 + inner);
        acc[j][0] += w0.x * xv.x; acc[j][1] += w0.y * xv.x; acc[j][2] += w0.z * xv.x;
        acc[j][0] += w0.w * xv.y; acc[j][1] += w1.x * xv.y; acc[j][2] += w1.y * xv.y;
        acc[j][0] += w1.z * xv.z; acc[j][1] += w1.w * xv.z; acc[j][2] += w2.x * xv.z;
        acc[j][0] += w2.y * xv.w; acc[j][1] += w2.z * xv.w; acc[j][2] += w2.w * xv.w;
    }
}

// Sampled linear: out[k] = Ws[k] . concat(x0, x1). Coalesced direct loads:
// lane (k,u) reads 16B at d = 4*(8i+u) -> consecutive lanes consecutive 16B.
template<int NODES>
__device__ __forceinline__ void linear_stage(const float* __restrict__ Wsg,
                                             const float* const* x0,
                                             const float* const* x1,
                                             float* part, int k, int u) {
    float4 wv[8];
#pragma unroll
    for (int i = 0; i < 8; ++i)
        wv[i] = *reinterpret_cast<const float4*>(Wsg + k * 256 + ((i * 8 + u) << 2));
#pragma unroll
    for (int n = 0; n < NODES; ++n) {
        float acc = 0.f;
#pragma unroll
        for (int i = 0; i < 8; ++i) {
            const float* xr = (i < 4) ? (x0[n] + (i << 5) + (u << 2))
                                      : (x1[n] + ((i - 4) << 5) + (u << 2));
            float4 xv = *reinterpret_cast<const float4*>(xr);
            acc += wv[i].x * xv.x + wv[i].y * xv.y + wv[i].z * xv.z + wv[i].w * xv.w;
        }
        part[(u * NODES + n) * 128 + k] = acc;
    }
}

template<int ROWS>
__device__ __forceinline__ void reduce_part(const float* part, float biasv,
                                            float aval, float* dst, int t) {
    if (t < ROWS * 128) {
        int r = t >> 7, kk = t & 127;
        float s = biasv;
#pragma unroll
        for (int u2 = 0; u2 < 8; ++u2) s += part[(u2 * ROWS + r) * 128 + kk];
        dst[r * 128 + kk] = prelu(s, aval);
    }
}

__global__ __launch_bounds__(1024) void encoder_fused(
    const float* __restrict__ points,
    const float* __restrict__ vec2, const float* __restrict__ vec1,
    const float* __restrict__ vec0,
    const float* __restrict__ Wp,  const float* __restrict__ bp,
    const float* __restrict__ aL,
    const float* __restrict__ Wb2, const float* __restrict__ bb2,
    const float* __restrict__ a2,
    const float* __restrict__ Wb1, const float* __restrict__ bb1,
    const float* __restrict__ Ws1, const float* __restrict__ bs1,
    const float* __restrict__ a1,
    const float* __restrict__ Wb0, const float* __restrict__ bb0,
    const float* __restrict__ Ws0, const float* __restrict__ bs0,
    const float* __restrict__ a0,
    const int* __restrict__ cl2, const int* __restrict__ cr2,
    const int* __restrict__ cl1, const int* __restrict__ cr1,
    const int* __restrict__ cs1,
    const int* __restrict__ cl0, const int* __restrict__ cr0,
    const int* __restrict__ cs0,
    float* __restrict__ out,
    int N3, int N2, int N1)
{
    __shared__ float wlds[2][12288];   // 2 x 48KB weight chunk buffers
    __shared__ float leaf[12][DIM];
    __shared__ float h2s[5][DIM];
    __shared__ float t1s[2][DIM];
    __shared__ float h1s[2][DIM];
    __shared__ float h0s[DIM];
    __shared__ float part[8 * 5 * DIM];
    __shared__ int   ljs[12];

    const int b = blockIdx.x;
    const int t = threadIdx.x;
    const int k  = t >> 3;    // output channel 0..127
    const int u  = t & 7;     // d-subchunk 0..7
    const int kk = t & 127;   // channel for per-channel preloads / leaf

    // ---- uniform index chain (scalar loads) ----
    const int m0 = cl0[0], m1 = cr0[0];
    int nj[5];
    nj[0] = cl1[m0]; nj[1] = cr1[m0];
    nj[2] = cl1[m1]; nj[3] = cr1[m1];
    nj[4] = cs0[0];
    if (t == 0) {
        ljs[0] = cl2[nj[0]]; ljs[1] = cr2[nj[0]];
        ljs[2] = cl2[nj[1]]; ljs[3] = cr2[nj[1]];
        ljs[4] = cl2[nj[2]]; ljs[5] = cr2[nj[2]];
        ljs[6] = cl2[nj[3]]; ljs[7] = cr2[nj[3]];
        ljs[8] = cl2[nj[4]]; ljs[9] = cr2[nj[4]];
        ljs[10] = cs1[m0];   ljs[11] = cs1[m1];
    }

    // ---- early preloads (uniform -> s_load; per-kk -> retired early) ----
    const float aLv = aL[0], a2v = a2[0], a1v = a1[0], a0v = a0[0];
    const float wp0 = Wp[kk * 3 + 0], wp1 = Wp[kk * 3 + 1], wp2 = Wp[kk * 3 + 2];
    const float bpv = bp[kk];
    const float bb2v = bb2[kk], bb1v = bb1[kk], bs1v = bs1[kk];
    const float bb0v = bb0[kk], bs0v = bs0[kk];
    float v2r[5][3], v1r[2][3], v0r[3];
#pragma unroll
    for (int j = 0; j < 5; ++j) {
        size_t vb = ((size_t)b * N2 + nj[j]) * 3;
        v2r[j][0] = vec2[vb]; v2r[j][1] = vec2[vb + 1]; v2r[j][2] = vec2[vb + 2];
    }
    {
        size_t vb0 = ((size_t)b * N1 + m0) * 3, vb1 = ((size_t)b * N1 + m1) * 3;
        v1r[0][0] = vec1[vb0]; v1r[0][1] = vec1[vb0 + 1]; v1r[0][2] = vec1[vb0 + 2];
        v1r[1][0] = vec1[vb1]; v1r[1][1] = vec1[vb1 + 1]; v1r[1][2] = vec1[vb1 + 2];
    }
    v0r[0] = vec0[b * 3]; v0r[1] = vec0[b * 3 + 1]; v0r[2] = vec0[b * 3 + 2];

    __syncthreads();                      // ljs visible

    // prefetch first Wb2 chunk; overlaps leaf stage
    stage_wb_chunk(Wb2, 0, wlds[0], t);

    // ---- leaf rows ----
    for (int idx = t; idx < 12 * DIM; idx += 1024) {
        int r = idx >> 7;
        size_t pb = ((size_t)b * N3 + ljs[r]) * 3;
        float p0 = points[pb], p1 = points[pb + 1], p2 = points[pb + 2];
        leaf[r][kk] = prelu(p0 * wp0 + p1 * wp1 + p2 * wp2 + bpv, aLv);
    }
    __syncthreads();                      // leaf visible (also drains chunk 0)

    // ---- layer 2 bilinear: 5 nodes ----
    float acc2[5][3] = {};
#pragma unroll
    for (int c = 0; c < 8; ++c) {
        if (c < 7) { stage_wb_chunk(Wb2, c + 1, wlds[(c + 1) & 1], t); WAITV3(); }
        else       { WAITV0(); }
        BARRIER();
        bilin_chunk<5>(wlds[c & 1], c, &leaf[0][0], k, u, acc2);
        BARRIER();
    }
    stage_wb_chunk(Wb1, 0, wlds[0], t);   // prefetch next layer during epilogue
#pragma unroll
    for (int j = 0; j < 5; ++j) {
        float z = v2r[j][0] * acc2[j][0] + v2r[j][1] * acc2[j][1] +
                  v2r[j][2] * acc2[j][2];
        part[(u * 5 + j) * 128 + k] = z;
    }
    BARRIER();
    reduce_part<5>(part, bb2v, a2v, &h2s[0][0], t);
    BARRIER();

    // ---- layer 1 bilinear: 2 nodes ----
    float acc1[2][3] = {};
#pragma unroll
    for (int c = 0; c < 8; ++c) {
        if (c < 7) { stage_wb_chunk(Wb1, c + 1, wlds[(c + 1) & 1], t); WAITV3(); }
        else       { WAITV0(); }
        BARRIER();
        bilin_chunk<2>(wlds[c & 1], c, &h2s[0][0], k, u, acc1);
        BARRIER();
    }
    stage_wb_chunk(Wb0, 0, wlds[0], t);   // prefetch root bilinear
#pragma unroll
    for (int n = 0; n < 2; ++n) {
        float z = v1r[n][0] * acc1[n][0] + v1r[n][1] * acc1[n][1] +
                  v1r[n][2] * acc1[n][2];
        part[(u * 2 + n) * 128 + k] = z;
    }
    BARRIER();
    reduce_part<2>(part, bb1v, a1v, &t1s[0][0], t);
    BARRIER();

    // ---- layer 1 sampled linear ----
    {
        const float* x0[2] = { &t1s[0][0], &t1s[1][0] };
        const float* x1[2] = { &leaf[10][0], &leaf[11][0] };
        linear_stage<2>(Ws1, x0, x1, part, k, u);
    }
    BARRIER();
    reduce_part<2>(part, bs1v, a1v, &h1s[0][0], t);
    BARRIER();

    // ---- root bilinear ----
    float acc0[1][3] = {};
#pragma unroll
    for (int c = 0; c < 8; ++c) {
        if (c < 7) { stage_wb_chunk(Wb0, c + 1, wlds[(c + 1) & 1], t); WAITV3(); }
        else       { WAITV0(); }
        BARRIER();
        bilin_chunk<1>(wlds[c & 1], c, &h1s[0][0], k, u, acc0);
        BARRIER();
    }
    {
        float z = v0r[0] * acc0[0][0] + v0r[1] * acc0[0][1] + v0r[2] * acc0[0][2];
        part[u * 128 + k] = z;
    }
    BARRIER();
    reduce_part<1>(part, bb0v, a0v, &h0s[0], t);
    BARRIER();

    // ---- root sampled linear -> output ----
    {
        const float* x0[1] = { &h0s[0] };
        const float* x1[1] = { &h2s[4][0] };
        linear_stage<1>(Ws0, x0, x1, part, k, u);
    }
    BARRIER();
    if (t < DIM) {
        float s = bs0v;
#pragma unroll
        for (int u2 = 0; u2 < 8; ++u2) s += part[u2 * 128 + t];
        out[(size_t)b * DIM + t] = prelu(s, a0v);
    }
}

// ---------------- launch ---------------------------------------------------
extern "C" void kernel_launch(void* const* d_in, const int* in_sizes, int n_in,
                              void* d_out, int out_size, void* d_ws, size_t ws_size,
                              hipStream_t stream)
{
    const float* points = (const float*)d_in[0];
    const float* vec2   = (const float*)d_in[1];
    const float* vec1   = (const float*)d_in[2];
    const float* vec0   = (const float*)d_in[3];
    const float* Wp     = (const float*)d_in[4];
    const float* bp     = (const float*)d_in[5];
    const float* a_leaf = (const float*)d_in[6];
    const float* Wb2    = (const float*)d_in[7];
    const float* bb2    = (const float*)d_in[8];
    const float* a2     = (const float*)d_in[9];
    const float* Wb1    = (const float*)d_in[10];
    const float* bb1    = (const float*)d_in[11];
    const float* Ws1    = (const float*)d_in[12];
    const float* bs1    = (const float*)d_in[13];
    const float* a1     = (const float*)d_in[14];
    const float* Wb0    = (const float*)d_in[15];
    const float* bb0    = (const float*)d_in[16];
    const float* Ws0    = (const float*)d_in[17];
    const float* bs0    = (const float*)d_in[18];
    const float* a0     = (const float*)d_in[19];
    const int* cl2 = (const int*)d_in[20];
    const int* cr2 = (const int*)d_in[21];
    const int* cl1 = (const int*)d_in[22];
    const int* cr1 = (const int*)d_in[23];
    const int* cs1 = (const int*)d_in[24];
    const int* cl0 = (const int*)d_in[25];
    const int* cr0 = (const int*)d_in[26];
    const int* cs0 = (const int*)d_in[27];

    const int B = 8, N3 = 131072, N2 = 65536, N1 = 1024;
    (void)d_ws; (void)ws_size; (void)in_sizes; (void)n_in; (void)out_size;

    encoder_fused<<<B, 1024, 0, stream>>>(
        points, vec2, vec1, vec0,
        Wp, bp, a_leaf,
        Wb2, bb2, a2,
        Wb1, bb1, Ws1, bs1, a1,
        Wb0, bb0, Ws0, bs0, a0,
        cl2, cr2, cl1, cr1, cs1, cl0, cr0, cs0,
        (float*)d_out, N3, N2, N1);
}

// Round 10
// 19.924 us; speedup vs baseline: 2.4740x; 1.2981x over previous
//
#include <hip/hip_runtime.h>
#include <hip/hip_bf16.h>
#include <cstdint>

#define DIM 128

__device__ __forceinline__ float prelu(float x, float a) {
    return x >= 0.f ? x : a * x;
}

// ---- per-thread weight fragment: 12 floats, PRIVATE to thread (k,u) ----
// Chunk c covers d in [32c,32c+32); thread (k,u) owns d-slice [32c+4u, +4),
// i.e. floats W[k*768 + c*96 + u*12 .. +11]. No LDS, no swizzle, no asm.
__device__ __forceinline__ void load_w3(const float* __restrict__ W, int c,
                                        int k, int u, float4 w[3]) {
    const float* p = W + (size_t)k * 768 + c * 96 + u * 12;
    w[0] = *reinterpret_cast<const float4*>(p);
    w[1] = *reinterpret_cast<const float4*>(p + 4);
    w[2] = *reinterpret_cast<const float4*>(p + 8);
}

// One 32-d chunk of bilinear accumulation from register weights.
// (x-side indexing identical to the round-4 kernel that passed.)
template<int J>
__device__ __forceinline__ void bilin_chunk_reg(const float4 w[3], int c,
                                                const float* xbase, int u,
                                                float acc[][3]) {
    const float wf[12] = { w[0].x, w[0].y, w[0].z, w[0].w,
                           w[1].x, w[1].y, w[1].z, w[1].w,
                           w[2].x, w[2].y, w[2].z, w[2].w };
    const int inner = ((c & 3) << 5) + (u << 2);
    const int half = c >> 2;   // which 128-row of the 256-wide concat
#pragma unroll
    for (int j = 0; j < J; ++j) {
        float4 xv = *reinterpret_cast<const float4*>(
            xbase + (2 * j + half) * 128 + inner);
        const float xf[4] = { xv.x, xv.y, xv.z, xv.w };
#pragma unroll
        for (int dl = 0; dl < 4; ++dl)
#pragma unroll
            for (int v = 0; v < 3; ++v)
                acc[j][v] += wf[dl * 3 + v] * xf[dl];
    }
}

// Round-4 epilogue: fold vec into part[], LDS tree-reduce over the 8 u-slices.
template<int ROWS>
__device__ __forceinline__ void reduce_part(const float* part, float biasv,
                                            float aval, float* dst, int t) {
    if (t < ROWS * 128) {
        int r = t >> 7, kk = t & 127;
        float p0 = part[(0 * ROWS + r) * 128 + kk];
        float p1 = part[(1 * ROWS + r) * 128 + kk];
        float p2 = part[(2 * ROWS + r) * 128 + kk];
        float p3 = part[(3 * ROWS + r) * 128 + kk];
        float p4 = part[(4 * ROWS + r) * 128 + kk];
        float p5 = part[(5 * ROWS + r) * 128 + kk];
        float p6 = part[(6 * ROWS + r) * 128 + kk];
        float p7 = part[(7 * ROWS + r) * 128 + kk];
        float s = ((p0 + p1) + (p2 + p3)) + ((p4 + p5) + (p6 + p7));
        dst[r * 128 + kk] = prelu(s + biasv, aval);
    }
}

// Round-4 sampled linear: out[k] = Ws[k].concat(x0,x1); coalesced wv loads.
template<int NODES>
__device__ __forceinline__ void linear_stage(const float* __restrict__ Wsg,
                                             const float* const* x0,
                                             const float* const* x1,
                                             float* part, int k, int u) {
    float4 wv[8];
#pragma unroll
    for (int i = 0; i < 8; ++i)
        wv[i] = *reinterpret_cast<const float4*>(Wsg + k * 256 + ((i * 8 + u) << 2));
#pragma unroll
    for (int n = 0; n < NODES; ++n) {
        float acc = 0.f;
#pragma unroll
        for (int i = 0; i < 8; ++i) {
            const float* xr = (i < 4) ? (x0[n] + (i << 5) + (u << 2))
                                      : (x1[n] + ((i - 4) << 5) + (u << 2));
            float4 xv = *reinterpret_cast<const float4*>(xr);
            acc += wv[i].x * xv.x + wv[i].y * xv.y + wv[i].z * xv.z + wv[i].w * xv.w;
        }
        part[(u * NODES + n) * 128 + k] = acc;
    }
}

__global__ __launch_bounds__(1024) void encoder_fused(
    const float* __restrict__ points,
    const float* __restrict__ vec2, const float* __restrict__ vec1,
    const float* __restrict__ vec0,
    const float* __restrict__ Wp,  const float* __restrict__ bp,
    const float* __restrict__ aL,
    const float* __restrict__ Wb2, const float* __restrict__ bb2,
    const float* __restrict__ a2,
    const float* __restrict__ Wb1, const float* __restrict__ bb1,
    const float* __restrict__ Ws1, const float* __restrict__ bs1,
    const float* __restrict__ a1,
    const float* __restrict__ Wb0, const float* __restrict__ bb0,
    const float* __restrict__ Ws0, const float* __restrict__ bs0,
    const float* __restrict__ a0,
    const int* __restrict__ cl2, const int* __restrict__ cr2,
    const int* __restrict__ cl1, const int* __restrict__ cr1,
    const int* __restrict__ cs1,
    const int* __restrict__ cl0, const int* __restrict__ cr0,
    const int* __restrict__ cs0,
    float* __restrict__ out,
    int N3, int N2, int N1)
{
    __shared__ float leaf[12][DIM];
    __shared__ float h2s[5][DIM];
    __shared__ float t1s[2][DIM];
    __shared__ float h1s[2][DIM];
    __shared__ float h0s[DIM];
    __shared__ float part[8 * 5 * DIM];
    __shared__ int   ljs[12];

    const int b = blockIdx.x;
    const int t = threadIdx.x;
    const int k  = t >> 3;    // output channel 0..127
    const int u  = t & 7;     // d-subchunk 0..7
    const int kk = t & 127;

    // ---- uniform index chain (round-4 verbatim) ----
    const int m0 = cl0[0], m1 = cr0[0];
    int nj[5];
    nj[0] = cl1[m0]; nj[1] = cr1[m0];
    nj[2] = cl1[m1]; nj[3] = cr1[m1];
    nj[4] = cs0[0];
    if (t == 0) {
        ljs[0] = cl2[nj[0]]; ljs[1] = cr2[nj[0]];
        ljs[2] = cl2[nj[1]]; ljs[3] = cr2[nj[1]];
        ljs[4] = cl2[nj[2]]; ljs[5] = cr2[nj[2]];
        ljs[6] = cl2[nj[3]]; ljs[7] = cr2[nj[3]];
        ljs[8] = cl2[nj[4]]; ljs[9] = cr2[nj[4]];
        ljs[10] = cs1[m0];   ljs[11] = cs1[m1];
    }

    // ---- preloads (round-4 verbatim) ----
    const float aLv = aL[0], a2v = a2[0], a1v = a1[0], a0v = a0[0];
    const float wp0 = Wp[kk * 3 + 0], wp1 = Wp[kk * 3 + 1], wp2 = Wp[kk * 3 + 2];
    const float bpv = bp[kk];
    const float bb2v = bb2[kk], bb1v = bb1[kk], bs1v = bs1[kk];
    const float bb0v = bb0[kk], bs0v = bs0[kk];
    float v2r[5][3], v1r[2][3], v0r[3];
#pragma unroll
    for (int j = 0; j < 5; ++j) {
        size_t vb = ((size_t)b * N2 + nj[j]) * 3;
        v2r[j][0] = vec2[vb]; v2r[j][1] = vec2[vb + 1]; v2r[j][2] = vec2[vb + 2];
    }
    {
        size_t vb0 = ((size_t)b * N1 + m0) * 3, vb1 = ((size_t)b * N1 + m1) * 3;
        v1r[0][0] = vec1[vb0]; v1r[0][1] = vec1[vb0 + 1]; v1r[0][2] = vec1[vb0 + 2];
        v1r[1][0] = vec1[vb1]; v1r[1][1] = vec1[vb1 + 1]; v1r[1][2] = vec1[vb1 + 2];
    }
    v0r[0] = vec0[b * 3]; v0r[1] = vec0[b * 3 + 1]; v0r[2] = vec0[b * 3 + 2];

    __syncthreads();                      // ljs visible

    // ---- leaf rows (round-4 verbatim) ----
    {
        for (int idx = t; idx < 12 * DIM; idx += 1024) {
            int r = idx >> 7;
            size_t pb = ((size_t)b * N3 + ljs[r]) * 3;
            float p0 = points[pb], p1 = points[pb + 1], p2 = points[pb + 2];
            leaf[r][kk] = prelu(p0 * wp0 + p1 * wp1 + p2 * wp2 + bpv, aLv);
        }
    }
    float4 wcur[3], wnxt[3];
    load_w3(Wb2, 0, k, u, wcur);          // prefetch chunk 0 while leaf settles
    __syncthreads();                      // leaf visible

    // ================ layer 2: 5 nodes ======================================
    float acc2[5][3] = {};
#pragma unroll
    for (int c = 0; c < 8; ++c) {
        if (c < 7) load_w3(Wb2, c + 1, k, u, wnxt);
        else       load_w3(Wb1, 0,     k, u, wnxt);   // cross-layer prefetch
        bilin_chunk_reg<5>(wcur, c, &leaf[0][0], u, acc2);
        wcur[0] = wnxt[0]; wcur[1] = wnxt[1]; wcur[2] = wnxt[2];
    }
#pragma unroll
    for (int j = 0; j < 5; ++j) {
        float z = v2r[j][0] * acc2[j][0] + v2r[j][1] * acc2[j][1] +
                  v2r[j][2] * acc2[j][2];
        part[(u * 5 + j) * 128 + k] = z;
    }
    __syncthreads();
    reduce_part<5>(part, bb2v, a2v, &h2s[0][0], t);
    __syncthreads();

    // ================ layer 1 bilinear: 2 nodes =============================
    float acc1[2][3] = {};
#pragma unroll
    for (int c = 0; c < 8; ++c) {
        if (c < 7) load_w3(Wb1, c + 1, k, u, wnxt);
        else       load_w3(Wb0, 0,     k, u, wnxt);   // prefetch root
        bilin_chunk_reg<2>(wcur, c, &h2s[0][0], u, acc1);
        wcur[0] = wnxt[0]; wcur[1] = wnxt[1]; wcur[2] = wnxt[2];
    }
#pragma unroll
    for (int n = 0; n < 2; ++n) {
        float z = v1r[n][0] * acc1[n][0] + v1r[n][1] * acc1[n][1] +
                  v1r[n][2] * acc1[n][2];
        part[(u * 2 + n) * 128 + k] = z;
    }
    __syncthreads();
    reduce_part<2>(part, bb1v, a1v, &t1s[0][0], t);
    __syncthreads();

    // ---- layer 1 sampled linear (round-4 verbatim) ----
    {
        const float* x0[2] = { &t1s[0][0], &t1s[1][0] };
        const float* x1[2] = { &leaf[10][0], &leaf[11][0] };
        linear_stage<2>(Ws1, x0, x1, part, k, u);
    }
    __syncthreads();
    reduce_part<2>(part, bs1v, a1v, &h1s[0][0], t);
    __syncthreads();

    // ================ root bilinear: 1 node =================================
    float acc0[1][3] = {};
#pragma unroll
    for (int c = 0; c < 8; ++c) {
        if (c < 7) load_w3(Wb0, c + 1, k, u, wnxt);
        bilin_chunk_reg<1>(wcur, c, &h1s[0][0], u, acc0);
        if (c < 7) { wcur[0] = wnxt[0]; wcur[1] = wnxt[1]; wcur[2] = wnxt[2]; }
    }
    {
        float z = v0r[0] * acc0[0][0] + v0r[1] * acc0[0][1] + v0r[2] * acc0[0][2];
        part[u * 128 + k] = z;
    }
    __syncthreads();
    reduce_part<1>(part, bb0v, a0v, &h0s[0], t);
    __syncthreads();

    // ---- root sampled linear -> output (round-4 verbatim) ----
    {
        const float* x0[1] = { &h0s[0] };
        const float* x1[1] = { &h2s[4][0] };
        linear_stage<1>(Ws0, x0, x1, part, k, u);
    }
    __syncthreads();
    if (t < DIM) {
        float p0 = part[0 * 128 + t], p1 = part[1 * 128 + t];
        float p2 = part[2 * 128 + t], p3 = part[3 * 128 + t];
        float p4 = part[4 * 128 + t], p5 = part[5 * 128 + t];
        float p6 = part[6 * 128 + t], p7 = part[7 * 128 + t];
        float s = ((p0 + p1) + (p2 + p3)) + ((p4 + p5) + (p6 + p7));
        out[(size_t)b * DIM + t] = prelu(s + bs0v, a0v);
    }
}

// ---------------- launch ---------------------------------------------------
extern "C" void kernel_launch(void* const* d_in, const int* in_sizes, int n_in,
                              void* d_out, int out_size, void* d_ws, size_t ws_size,
                              hipStream_t stream)
{
    const float* points = (const float*)d_in[0];
    const float* vec2   = (const float*)d_in[1];
    const float* vec1   = (const float*)d_in[2];
    const float* vec0   = (const float*)d_in[3];
    const float* Wp     = (const float*)d_in[4];
    const float* bp     = (const float*)d_in[5];
    const float* a_leaf = (const float*)d_in[6];
    const float* Wb2    = (const float*)d_in[7];
    const float* bb2    = (const float*)d_in[8];
    const float* a2     = (const float*)d_in[9];
    const float* Wb1    = (const float*)d_in[10];
    const float* bb1    = (const float*)d_in[11];
    const float* Ws1    = (const float*)d_in[12];
    const float* bs1    = (const float*)d_in[13];
    const float* a1     = (const float*)d_in[14];
    const float* Wb0    = (const float*)d_in[15];
    const float* bb0    = (const float*)d_in[16];
    const float* Ws0    = (const float*)d_in[17];
    const float* bs0    = (const float*)d_in[18];
    const float* a0     = (const float*)d_in[19];
    const int* cl2 = (const int*)d_in[20];
    const int* cr2 = (const int*)d_in[21];
    const int* cl1 = (const int*)d_in[22];
    const int* cr1 = (const int*)d_in[23];
    const int* cs1 = (const int*)d_in[24];
    const int* cl0 = (const int*)d_in[25];
    const int* cr0 = (const int*)d_in[26];
    const int* cs0 = (const int*)d_in[27];

    const int B = 8, N3 = 131072, N2 = 65536, N1 = 1024;
    (void)d_ws; (void)ws_size; (void)in_sizes; (void)n_in; (void)out_size;

    encoder_fused<<<B, 1024, 0, stream>>>(
        points, vec2, vec1, vec0,
        Wp, bp, a_leaf,
        Wb2, bb2, a2,
        Wb1, bb1, Ws1, bs1, a1,
        Wb0, bb0, Ws0, bs0, a0,
        cl2, cr2, cl1, cr1, cs1, cl0, cr0, cs0,
        (float*)d_out, N3, N2, N1);
}